// Round 8
// baseline (481.124 us; speedup 1.0000x reference)
//
#include <hip/hip_runtime.h>

// Problem constants (B=16, D=128, H=32, W=32, K=8192)
#define D 128
#define HW 1024
#define NROWS 16384
#define K 8192
#define NU 16   // 64-col units per block (1024-col k-split / 64)

// d_out layout (float offsets): z_q_st | indices | new_codebook | new_count | new_weight
#define OUT0 0
#define OUT1 2097152
#define OUT2 2113536
#define OUT3 3162112
#define OUT4 3170304

// d_ws layout (byte offsets)
#define WS_CNORM   0         // f32[8192]
#define WS_PACKED  32768     // u64[16384]
#define WS_CNT     163840    // u32[8192]
#define WS_CNT2    196608    // u32[8192]
#define WS_OFFS    229376    // u32[8193]
#define WS_IDX16   262400    // u16[16384]
#define WS_ROWLIST 295424    // u16[16384]

typedef __attribute__((ext_vector_type(8))) _Float16 half8;
typedef __attribute__((ext_vector_type(16))) float f32x16;
typedef unsigned short u16;
typedef unsigned int u32;
typedef unsigned long long u64;

// ---- async global->LDS, 16B per lane (dst = wave-uniform base + lane*16) ----
__device__ __forceinline__ void gld16(const u16* gsrc, u16* ldst) {
    __builtin_amdgcn_global_load_lds(
        (const __attribute__((address_space(1))) unsigned int*)gsrc,
        (__attribute__((address_space(3))) unsigned int*)ldst,
        16, 0, 0);
}

// ---- cb prep: fp16 hi/lo split + cnorm + zero dw/cnt/cnt2 + packed init ----
// B layout: [unit g(128)][ Bh: [kk(16)][col(64)][j(8)] | Bl: same ] (32 KiB/unit)
__global__ __launch_bounds__(256) void k_prep_cb(const float* __restrict__ cb,
                                                 u16* __restrict__ Bg,
                                                 float* __restrict__ cnorm,
                                                 u64* __restrict__ packed,
                                                 u32* __restrict__ cnt,
                                                 u32* __restrict__ cnt2,
                                                 float* __restrict__ dw) {
    const int tid = threadIdx.x;
    int kk = tid & 15;
    int k = blockIdx.x * 16 + (tid >> 4);
    const float* src = cb + (size_t)k * D + kk * 8;
    half8 h, l;
    float s = 0.f;
#pragma unroll
    for (int j = 0; j < 8; ++j) {
        float v = src[j];
        s += v * v;
        _Float16 hv = (_Float16)v;              // RN f32->f16
        _Float16 lv = (_Float16)(v - (float)hv);
        h[j] = hv;
        l[j] = lv;
    }
    int g = k >> 6, col = k & 63;
    size_t offH = (size_t)g * 16384 + ((size_t)kk * 64 + col) * 8;
    *(half8*)((_Float16*)Bg + offH) = h;
    *(half8*)((_Float16*)Bg + offH + 8192) = l;
#pragma unroll
    for (int off = 8; off > 0; off >>= 1) s += __shfl_down(s, off);
    if (kk == 0) cnorm[k] = s;
    // zero dw: 512 blocks x 256 thr x 8 floats = K*D exactly
    float4 z4 = {0.f, 0.f, 0.f, 0.f};
    size_t zi = ((size_t)blockIdx.x * 256 + tid) * 8;
    *(float4*)(dw + zi) = z4;
    *(float4*)(dw + zi + 4) = z4;
    int gid = blockIdx.x * 256 + tid;
    if (gid < NROWS) packed[gid] = ~0ull;       // +inf sentinel
    if (gid < K) { cnt[gid] = 0u; cnt2[gid] = 0u; }
}

// ---- main: in-kernel A-split + 3-pass fp16-split GEMM + fused argmin ----
// grid: 64 rowgroups (256 rows) x 8 ksplits (1024 cols) = 512 blocks = 2/CU.
// block: 512 thr = 8 waves (wy 0..3 x wx 0..1); wave = 64 rows x 32 cols
// (2 row-tiles -> each B fragment feeds 6 MFMAs). LDS: 2 x 32 KiB units,
// prefetch in flight across raw s_barrier via vmcnt(4). VGPR capped <=128
// by launch_bounds -> 4 waves/SIMD -> 16 waves/CU.
__global__ __launch_bounds__(512, 4) void k_argmin_mfma(
        const float* __restrict__ z_e,
        const u16* __restrict__ Bg,
        const float* __restrict__ cnorm, u64* __restrict__ packed) {
    __shared__ u16 lds[2][16384];               // 2 x 32 KiB

    const int tid = threadIdx.x;
    const int ln  = tid & 63;
    const int l31 = ln & 31;
    const int lh  = ln >> 5;                    // k-half select within frag
    const int wv  = tid >> 6;
    const int wy  = wv & 3;                     // 64-row band
    const int wx  = wv >> 2;                    // 32-col half

    const int rg = blockIdx.x >> 3;             // 64 rowgroups x 256 rows
    const int k0 = (blockIdx.x & 7) * 1024;     // col split
    const int g0 = k0 >> 6;                     // first 64-col B-unit

    // ---- load & fp16-split A rows for both row-tiles ----
    half8 Ah[2][8], Al[2][8];
#pragma unroll
    for (int rt = 0; rt < 2; ++rt) {
        const int rowA = rg * 256 + wy * 64 + rt * 32 + l31;
        const float* za = z_e + (size_t)(rowA >> 10) * (D * HW) + (rowA & 1023);
#pragma unroll
        for (int ks = 0; ks < 8; ++ks) {
            half8 h, l;
#pragma unroll
            for (int j = 0; j < 8; ++j) {
                float v = za[(size_t)(ks * 16 + lh * 8 + j) * HW];
                _Float16 hv = (_Float16)v;
                _Float16 lv = (_Float16)(v - (float)hv);
                h[j] = hv;
                l[j] = lv;
            }
            Ah[rt][ks] = h;
            Al[rt][ks] = l;
        }
    }

    // ---- stage unit 0 (32 KiB, 4 gld16/thread at 512 thr) ----
    {
        const u16* src = Bg + (size_t)g0 * 16384;
#pragma unroll
        for (int r = 0; r < 4; ++r)
            gld16(src + (r * 512 + tid) * 8, lds[0] + (r * 512 + tid) * 8);
    }

    float minv[2][16];
    int   mini[2][16];
#pragma unroll
    for (int rt = 0; rt < 2; ++rt)
#pragma unroll
        for (int r = 0; r < 16; ++r) { minv[rt][r] = INFINITY; mini[rt][r] = 0; }

    const int bo_base = wx * 32 + l31;

#pragma unroll 1
    for (int u = 0; u < NU; ++u) {
        const int colv = k0 + u * 64 + wx * 32 + l31;
        float cn0 = cnorm[colv];

        if (u + 1 < NU) {
            const u16* src = Bg + (size_t)(g0 + u + 1) * 16384;
            u16* dst = lds[(u + 1) & 1];
#pragma unroll
            for (int r = 0; r < 4; ++r)
                gld16(src + (r * 512 + tid) * 8, dst + (r * 512 + tid) * 8);
            // wait for *this* unit's stage; next unit's 4 loads stay in flight
            asm volatile("s_waitcnt vmcnt(4)" ::: "memory");
        } else {
            asm volatile("s_waitcnt vmcnt(0)" ::: "memory");
        }
        asm volatile("s_barrier" ::: "memory");

        const _Float16* bh = (const _Float16*)lds[u & 1];
        const _Float16* bl = bh + 8192;
        f32x16 acc0 = {}, acc1 = {};
#pragma unroll
        for (int ks = 0; ks < 8; ++ks) {
            const int bo = ((ks * 2 + lh) * 64 + bo_base) * 8;
            half8 vbl = *(const half8*)(bl + bo);
            half8 vbh = *(const half8*)(bh + bo);
            acc0 = __builtin_amdgcn_mfma_f32_32x32x16_f16(Ah[0][ks], vbl, acc0, 0, 0, 0);
            acc1 = __builtin_amdgcn_mfma_f32_32x32x16_f16(Ah[1][ks], vbl, acc1, 0, 0, 0);
            acc0 = __builtin_amdgcn_mfma_f32_32x32x16_f16(Ah[0][ks], vbh, acc0, 0, 0, 0);
            acc1 = __builtin_amdgcn_mfma_f32_32x32x16_f16(Ah[1][ks], vbh, acc1, 0, 0, 0);
            acc0 = __builtin_amdgcn_mfma_f32_32x32x16_f16(Al[0][ks], vbh, acc0, 0, 0, 0);
            acc1 = __builtin_amdgcn_mfma_f32_32x32x16_f16(Al[1][ks], vbh, acc1, 0, 0, 0);
        }

#pragma unroll
        for (int r = 0; r < 16; ++r) {
            float d0 = fmaf(-2.0f, acc0[r], cn0);
            float d1 = fmaf(-2.0f, acc1[r], cn0);
            if (d0 < minv[0][r]) { minv[0][r] = d0; mini[0][r] = colv; }
            if (d1 < minv[1][r]) { minv[1][r] = d1; mini[1][r] = colv; }
        }
        asm volatile("s_barrier" ::: "memory");
    }

#pragma unroll
    for (int rt = 0; rt < 2; ++rt)
#pragma unroll
        for (int r = 0; r < 16; ++r) {
            float v = minv[rt][r];
            int ix = mini[rt][r];
#pragma unroll
            for (int off = 1; off < 32; off <<= 1) {
                float v2 = __shfl_xor(v, off);
                int i2 = __shfl_xor(ix, off);
                if (v2 < v || (v2 == v && i2 < ix)) { v = v2; ix = i2; }
            }
            if (l31 == 0) {
                // C/D row map (m74/m101): row32 = (r&3) + 8*(r>>2) + 4*lh
                int row = rg * 256 + wy * 64 + rt * 32 + 4 * lh + (r & 3) + 8 * (r >> 2);
                unsigned int uenc = __float_as_uint(v);
                uenc = (uenc & 0x80000000u) ? ~uenc : (uenc | 0x80000000u);
                u64 pk = ((u64)uenc << 13) | (u64)(unsigned)ix;
                atomicMin(&packed[row], pk);
            }
        }
}

// ---- phase1: decode indices, count, and transpose z_e -> z_flat (N x D) ----
__global__ __launch_bounds__(256) void k_phase1(const float* __restrict__ z_e,
                                                const u64* __restrict__ packed,
                                                float* __restrict__ out1,
                                                u32* __restrict__ cnt,
                                                u16* __restrict__ idx16,
                                                float* __restrict__ zf) {
    __shared__ float Zt[64 * 132];
    const int tid = threadIdx.x;
    const int n0 = blockIdx.x * 64;
    const int bb = n0 >> 10, p0 = n0 & 1023;

    if (tid < 64) {
        int ix = (int)(packed[n0 + tid] & 0x1FFFull);
        idx16[n0 + tid] = (u16)ix;
        out1[n0 + tid] = (float)ix;
        atomicAdd(&cnt[ix], 1u);
    }

    const float* zb = z_e + (size_t)bb * (D * HW) + p0;
    for (int i = tid; i < 2048; i += 256) {
        int d = i >> 4;
        int r4 = (i & 15) << 2;
        float4 v = *(const float4*)(zb + (size_t)d * HW + r4);
        Zt[(r4 + 0) * 132 + d] = v.x;
        Zt[(r4 + 1) * 132 + d] = v.y;
        Zt[(r4 + 2) * 132 + d] = v.z;
        Zt[(r4 + 3) * 132 + d] = v.w;
    }
    __syncthreads();
    for (int i = tid; i < 2048; i += 256) {
        int r = i >> 5, dq = (i & 31) << 2;
        float4 v = *(const float4*)(&Zt[r * 132 + dq]);
        *(float4*)(zf + (size_t)(n0 + r) * D + dq) = v;
    }
}

// ---- scan: exclusive prefix sum of cnt[8192] -> offs[8193] (1 block) ----
__global__ __launch_bounds__(256) void k_scan(const u32* __restrict__ cnt,
                                              u32* __restrict__ offs) {
    __shared__ u32 ssum[256];
    const int t = threadIdx.x;
    u32 s = 0;
    for (int j = 0; j < 32; ++j) s += cnt[t * 32 + j];
    ssum[t] = s;
    __syncthreads();
    u32 acc = s;
    for (int off = 1; off < 256; off <<= 1) {
        u32 v = (t >= off) ? ssum[t - off] : 0u;
        __syncthreads();
        acc += v;
        ssum[t] = acc;
        __syncthreads();
    }
    u32 run = acc - s;                          // exclusive prefix of this chunk
    for (int j = 0; j < 32; ++j) {
        offs[t * 32 + j] = run;
        run += cnt[t * 32 + j];
    }
    if (t == 255) offs[K] = run;
}

// ---- scatter: build code-grouped row list ----
__global__ __launch_bounds__(256) void k_scatter(const u16* __restrict__ idx16,
                                                 const u32* __restrict__ offs,
                                                 u32* __restrict__ cnt2,
                                                 u16* __restrict__ rowlist) {
    int n = blockIdx.x * 256 + threadIdx.x;
    int ix = idx16[n];
    u32 pos = offs[ix] + atomicAdd(&cnt2[ix], 1u);
    rowlist[pos] = (u16)n;
}

// ---- dw: segmented sum over code-grouped rows; run-accumulated in regs ----
// 1024 waves x 16 list positions; lanes cover d (ln, ln+64). Flush per run
// (atomicAdd): hot-code per-address serialization = count/16, not count.
__global__ __launch_bounds__(256) void k_dw(const float* __restrict__ zf,
                                            const u16* __restrict__ rowlist,
                                            const u16* __restrict__ idx16,
                                            float* __restrict__ dw) {
    const int tid = threadIdx.x;
    const int ln = tid & 63;
    const int w = (blockIdx.x * 256 + tid) >> 6;    // 0..1023
    float a0 = 0.f, a1 = 0.f;
    int prev = -1;
    for (int i = w * 16; i < w * 16 + 16; ++i) {
        int n = rowlist[i];
        int k = idx16[n];
        float v0 = zf[(size_t)n * D + ln];
        float v1 = zf[(size_t)n * D + ln + 64];
        if (k != prev) {
            if (prev >= 0) {
                atomicAdd(&dw[(size_t)prev * D + ln], a0);
                atomicAdd(&dw[(size_t)prev * D + ln + 64], a1);
            }
            prev = k; a0 = v0; a1 = v1;
        } else {
            a0 += v0; a1 += v1;
        }
    }
    if (prev >= 0) {
        atomicAdd(&dw[(size_t)prev * D + ln], a0);
        atomicAdd(&dw[(size_t)prev * D + ln + 64], a1);
    }
}

// ---- last: fused z_q_st write (overwrites z_flat region) + EMA update ----
__global__ __launch_bounds__(256) void k_last(const float* __restrict__ z_e,
                                              const float* __restrict__ cb,
                                              const u16* __restrict__ idx16,
                                              const u32* __restrict__ cnt,
                                              const float* __restrict__ ema_count,
                                              const float* __restrict__ ema_weight,
                                              float* __restrict__ out0,
                                              float* __restrict__ out2,
                                              float* __restrict__ out3,
                                              float* __restrict__ out4) {
    const int tid = threadIdx.x;
    if (blockIdx.x < 256) {
        __shared__ int idxS[64];
        const int n0 = blockIdx.x * 64;
        const int bb = n0 >> 10, p0 = n0 & 1023;
        if (tid < 64) idxS[tid] = idx16[n0 + tid];
        __syncthreads();
        const float* zb = z_e + (size_t)bb * (D * HW) + p0;
        float* ob = out0 + (size_t)bb * (D * HW) + p0;
        for (int i = tid; i < 64 * D; i += 256) {
            int d = i >> 6, r = i & 63;
            float z = zb[(size_t)d * HW + r];
            float c = cb[(size_t)idxS[r] * D + d];
            ob[(size_t)d * HW + r] = z + (c - z);
        }
    } else {
        int gid = (blockIdx.x - 256) * 256 + tid;   // over K*D
        int k = gid >> 7, d = gid & 127;
        float nc = 0.99f * ema_count[k] + 0.01f * (float)cnt[k];
        float nw = 0.99f * ema_weight[gid] + 0.01f * out4[gid];
        out4[gid] = nw;
        out2[gid] = nw / fmaxf(nc, 1.0f);
        if (d == 0) out3[k] = nc;
    }
}

extern "C" void kernel_launch(void* const* d_in, const int* in_sizes, int n_in,
                              void* d_out, int out_size, void* d_ws, size_t ws_size,
                              hipStream_t stream) {
    const float* z_e        = (const float*)d_in[0];
    const float* cb         = (const float*)d_in[1];
    const float* ema_count  = (const float*)d_in[2];
    const float* ema_weight = (const float*)d_in[3];
    float* out = (float*)d_out;
    char* ws = (char*)d_ws;

    float* cnorm   = (float*)(ws + WS_CNORM);
    u64*   packed  = (u64*)(ws + WS_PACKED);
    u32*   cnt     = (u32*)(ws + WS_CNT);
    u32*   cnt2    = (u32*)(ws + WS_CNT2);
    u32*   offs    = (u32*)(ws + WS_OFFS);
    u16*   idx16   = (u16*)(ws + WS_IDX16);
    u16*   rowlist = (u16*)(ws + WS_ROWLIST);

    // fp16-split B lives in out2 (4 MB); z_flat lives in out0 (8 MB) until
    // k_last overwrites it with z_q_st.
    u16* Bg = (u16*)(out + OUT2);
    float* zf = out + OUT0;

    k_prep_cb    <<<K / 16,     256, 0, stream>>>(cb, Bg, cnorm, packed, cnt, cnt2,
                                                  out + OUT4);
    k_argmin_mfma<<<512,        512, 0, stream>>>(z_e, Bg, cnorm, packed);
    k_phase1     <<<NROWS / 64, 256, 0, stream>>>(z_e, packed, out + OUT1, cnt,
                                                  idx16, zf);
    k_scan       <<<1,          256, 0, stream>>>(cnt, offs);
    k_scatter    <<<NROWS / 256,256, 0, stream>>>(idx16, offs, cnt2, rowlist);
    k_dw         <<<256,        256, 0, stream>>>(zf, rowlist, idx16, out + OUT4);
    k_last       <<<256 + (K * D) / 256, 256, 0, stream>>>(z_e, cb, idx16, cnt,
                                                  ema_count, ema_weight,
                                                  out + OUT0, out + OUT2,
                                                  out + OUT3, out + OUT4);
}

// Round 9
// 212.782 us; speedup vs baseline: 2.2611x; 2.2611x over previous
//
#include <hip/hip_runtime.h>

// Problem constants (B=16, D=128, H=32, W=32, K=8192)
#define D 128
#define HW 1024
#define NROWS 16384
#define K 8192
#define NU 32   // 64-col units per block (2048-col k-split / 64)

// d_out layout (float offsets): z_q_st | indices | new_codebook | new_count | new_weight
#define OUT0 0
#define OUT1 2097152
#define OUT2 2113536
#define OUT3 3162112
#define OUT4 3170304

// d_ws layout (byte offsets)
#define WS_CNORM   0         // f32[8192]
#define WS_PACKED  32768     // u64[16384]
#define WS_CNT     163840    // u32[8192]
#define WS_RANK16  196608    // u16[16384]
#define WS_OFFS    229376    // u32[8193]
#define WS_IDX16   262400    // u16[16384]
#define WS_ROWLIST 295424    // u16[16384]

typedef __attribute__((ext_vector_type(8))) _Float16 half8;
typedef __attribute__((ext_vector_type(16))) float f32x16;
typedef unsigned short u16;
typedef unsigned int u32;
typedef unsigned long long u64;

// ---- async global->LDS, 16B per lane (dst = wave-uniform base + lane*16) ----
__device__ __forceinline__ void gld16(const u16* gsrc, u16* ldst) {
    __builtin_amdgcn_global_load_lds(
        (const __attribute__((address_space(1))) unsigned int*)gsrc,
        (__attribute__((address_space(3))) unsigned int*)ldst,
        16, 0, 0);
}

// ---- fused prep: blocks [0,512) codebook-split + cnorm + dw-zero;
//      blocks [512,1536) z-split + packed-init + cnt-zero ----
// B layout: [unit g(128)][ Bh: [kk(16)][col(64)][j(8)] | Bl: same ] (32 KiB/unit)
// A layout: [rg(128)][band(4)][ks(8)][kh(2)][row(32)][j(8)]
__global__ __launch_bounds__(256) void k_prep(const float* __restrict__ cb,
                                              const float* __restrict__ z_e,
                                              u16* __restrict__ Bg,
                                              float* __restrict__ cnorm,
                                              u16* __restrict__ Ah, u16* __restrict__ Al,
                                              u64* __restrict__ packed,
                                              u32* __restrict__ cnt,
                                              float* __restrict__ dw) {
    const int tid = threadIdx.x;
    if (blockIdx.x < 512) {
        int kk = tid & 15;
        int k = blockIdx.x * 16 + (tid >> 4);
        const float* src = cb + (size_t)k * D + kk * 8;
        half8 h, l;
        float s = 0.f;
#pragma unroll
        for (int j = 0; j < 8; ++j) {
            float v = src[j];
            s += v * v;
            _Float16 hv = (_Float16)v;              // RN f32->f16
            _Float16 lv = (_Float16)(v - (float)hv);
            h[j] = hv;
            l[j] = lv;
        }
        int g = k >> 6, col = k & 63;
        size_t offH = (size_t)g * 16384 + ((size_t)kk * 64 + col) * 8;
        *(half8*)((_Float16*)Bg + offH) = h;
        *(half8*)((_Float16*)Bg + offH + 8192) = l;
#pragma unroll
        for (int off = 8; off > 0; off >>= 1) s += __shfl_down(s, off);
        if (kk == 0) cnorm[k] = s;
        // zero dw: 512 blocks x 256 thr x 8 floats = K*D exactly
        float4 z4 = {0.f, 0.f, 0.f, 0.f};
        size_t zi = ((size_t)blockIdx.x * 256 + tid) * 8;
        *(float4*)(dw + zi) = z4;
        *(float4*)(dw + zi + 4) = z4;
    } else {
        int gid = (blockIdx.x - 512) * 256 + tid;   // NROWS*16 threads
        int n  = gid & (NROWS - 1);                 // lane-contiguous n -> coalesced
        int kk = gid >> 14;                         // 0..15
        int b = n >> 10, hw = n & 1023;
        const float* src = z_e + ((size_t)b * D + kk * 8) * HW + hw;
        half8 h, l;
#pragma unroll
        for (int j = 0; j < 8; ++j) {
            float v = src[(size_t)j * HW];
            _Float16 hv = (_Float16)v;
            _Float16 lv = (_Float16)(v - (float)hv);
            h[j] = hv;
            l[j] = lv;
        }
        int rg = n >> 7, band = (n >> 5) & 3, row = n & 31;
        size_t off = (((((size_t)rg * 4 + band) * 8 + (kk >> 1)) * 2 + (kk & 1)) * 32 + row) * 8;
        *(half8*)(Ah + off) = h;
        *(half8*)(Al + off) = l;
        if (kk == 0) {
            packed[n] = ~0ull;                      // +inf sentinel
            if (n < K) cnt[n] = 0u;
        }
    }
}

// ---- main: 3-pass fp16-split distance GEMM + fused argmin (r5 config) ----
// grid: 128 rowgroups (128 rows) x 4 ksplits = 512 blocks = 2/CU; 512 thr =
// 8 waves (wy 0..3 x wx 0..1); wave = 32 rows x 32 cols, A-frags in regs
// (64 VGPR). B staged in 32 KiB units, 2x32 KiB dbuf; prefetch stays in
// flight across raw s_barrier via vmcnt(4). 16 waves/CU.
__global__ __launch_bounds__(512, 4) void k_argmin_mfma(
        const u16* __restrict__ Ahg, const u16* __restrict__ Alg,
        const u16* __restrict__ Bg,
        const float* __restrict__ cnorm, u64* __restrict__ packed) {
    __shared__ u16 lds[2][16384];               // 2 x 32 KiB

    const int tid = threadIdx.x;
    const int ln  = tid & 63;
    const int l31 = ln & 31;
    const int lh  = ln >> 5;                    // k-half select within frag
    const int wv  = tid >> 6;                   // 0..7
    const int wy  = wv & 3;                     // row band 0..3
    const int wx  = wv >> 2;                    // col half 0..1

    const int rg = blockIdx.x >> 2;             // 128 rowgroups x 128 rows
    const int k0 = (blockIdx.x & 3) * 2048;     // col split
    const int g0 = k0 >> 6;                     // first 64-col B-unit

    // ---- A fragments -> registers (read once from global; 64 VGPRs) ----
    half8 Ah[8], Al[8];
#pragma unroll
    for (int ks = 0; ks < 8; ++ks) {
        size_t off = ((((size_t)(rg * 4 + wy) * 8 + ks) * 2 + lh) * 32 + l31) * 8;
        Ah[ks] = *(const half8*)((const _Float16*)Ahg + off);
        Al[ks] = *(const half8*)((const _Float16*)Alg + off);
    }

    // ---- stage unit 0 (32 KiB, 4 gld16/thread) ----
    {
        const u16* src = Bg + (size_t)g0 * 16384;
#pragma unroll
        for (int r = 0; r < 4; ++r)
            gld16(src + ((size_t)r * 512 + tid) * 8, lds[0] + (r * 512 + tid) * 8);
    }

    float minv[16];
    int   mini[16];
#pragma unroll
    for (int r = 0; r < 16; ++r) { minv[r] = INFINITY; mini[r] = 0; }

    const int bo_base = wx * 32 + l31;

#pragma unroll 1
    for (int u = 0; u < NU; ++u) {
        const int colv = k0 + u * 64 + wx * 32 + l31;
        float cn0 = cnorm[colv];

        if (u + 1 < NU) {
            const u16* src = Bg + (size_t)(g0 + u + 1) * 16384;
            u16* dst = lds[(u + 1) & 1];
#pragma unroll
            for (int r = 0; r < 4; ++r)
                gld16(src + ((size_t)r * 512 + tid) * 8, dst + (r * 512 + tid) * 8);
            // wait for *this* unit's stage; next unit's 4 loads stay in flight
            asm volatile("s_waitcnt vmcnt(4)" ::: "memory");
        } else {
            asm volatile("s_waitcnt vmcnt(0)" ::: "memory");
        }
        asm volatile("s_barrier" ::: "memory");

        const _Float16* bh = (const _Float16*)lds[u & 1];
        const _Float16* bl = bh + 8192;
        f32x16 acc = {};
#pragma unroll
        for (int ks = 0; ks < 8; ++ks) {
            const int bo = ((ks * 2 + lh) * 64 + bo_base) * 8;
            half8 vbl = *(const half8*)(bl + bo);
            half8 vbh = *(const half8*)(bh + bo);
            acc = __builtin_amdgcn_mfma_f32_32x32x16_f16(Ah[ks], vbl, acc, 0, 0, 0);
            acc = __builtin_amdgcn_mfma_f32_32x32x16_f16(Ah[ks], vbh, acc, 0, 0, 0);
            acc = __builtin_amdgcn_mfma_f32_32x32x16_f16(Al[ks], vbh, acc, 0, 0, 0);
        }

        // fold dist = cnorm - 2*dot into running argmin
#pragma unroll
        for (int r = 0; r < 16; ++r) {
            float d0 = fmaf(-2.0f, acc[r], cn0);
            if (d0 < minv[r]) { minv[r] = d0; mini[r] = colv; }
        }
        // all waves done reading lds[u&1] before next iter's prefetch overwrite
        asm volatile("s_barrier" ::: "memory");
    }

    // ---- reduce across the 32 l31-lanes sharing each output row ----
#pragma unroll
    for (int r = 0; r < 16; ++r) {
        float v = minv[r];
        int ix = mini[r];
#pragma unroll
        for (int off = 1; off < 32; off <<= 1) {
            float v2 = __shfl_xor(v, off);
            int i2 = __shfl_xor(ix, off);
            if (v2 < v || (v2 == v && i2 < ix)) { v = v2; ix = i2; }
        }
        if (l31 == 0) {
            // C/D row map (m74/m101): row32 = (r&3) + 8*(r>>2) + 4*lh
            int row = rg * 128 + wy * 32 + 4 * lh + (r & 3) + 8 * (r >> 2);
            unsigned int uenc = __float_as_uint(v);
            uenc = (uenc & 0x80000000u) ? ~uenc : (uenc | 0x80000000u);  // monotonic
            u64 pk = ((u64)uenc << 13) | (u64)(unsigned)ix;
            atomicMin(&packed[row], pk);
        }
    }
}

// ---- phase1: decode indices, count+rank, transpose z_e -> z_flat (N x D) ----
__global__ __launch_bounds__(256) void k_phase1(const float* __restrict__ z_e,
                                                const u64* __restrict__ packed,
                                                float* __restrict__ out1,
                                                u32* __restrict__ cnt,
                                                u16* __restrict__ idx16,
                                                u16* __restrict__ rank16,
                                                float* __restrict__ zf) {
    __shared__ float Zt[64 * 132];
    const int tid = threadIdx.x;
    const int n0 = blockIdx.x * 64;
    const int bb = n0 >> 10, p0 = n0 & 1023;

    if (tid < 64) {
        int ix = (int)(packed[n0 + tid] & 0x1FFFull);
        idx16[n0 + tid] = (u16)ix;
        out1[n0 + tid] = (float)ix;
        u32 old = atomicAdd(&cnt[ix], 1u);      // old value = unique rank in code
        rank16[n0 + tid] = (u16)old;
    }

    const float* zb = z_e + (size_t)bb * (D * HW) + p0;
    for (int i = tid; i < 2048; i += 256) {
        int d = i >> 4;
        int r4 = (i & 15) << 2;
        float4 v = *(const float4*)(zb + (size_t)d * HW + r4);
        Zt[(r4 + 0) * 132 + d] = v.x;
        Zt[(r4 + 1) * 132 + d] = v.y;
        Zt[(r4 + 2) * 132 + d] = v.z;
        Zt[(r4 + 3) * 132 + d] = v.w;
    }
    __syncthreads();
    for (int i = tid; i < 2048; i += 256) {
        int r = i >> 5, dq = (i & 31) << 2;
        float4 v = *(const float4*)(&Zt[r * 132 + dq]);
        *(float4*)(zf + (size_t)(n0 + r) * D + dq) = v;
    }
}

// ---- scan: exclusive prefix sum of cnt[8192] -> offs[8193] (1 block) ----
__global__ __launch_bounds__(256) void k_scan(const u32* __restrict__ cnt,
                                              u32* __restrict__ offs) {
    __shared__ u32 ssum[256];
    const int t = threadIdx.x;
    u32 s = 0;
    for (int j = 0; j < 32; ++j) s += cnt[t * 32 + j];
    ssum[t] = s;
    __syncthreads();
    u32 acc = s;
    for (int off = 1; off < 256; off <<= 1) {
        u32 v = (t >= off) ? ssum[t - off] : 0u;
        __syncthreads();
        acc += v;
        ssum[t] = acc;
        __syncthreads();
    }
    u32 run = acc - s;                          // exclusive prefix of this chunk
    for (int j = 0; j < 32; ++j) {
        offs[t * 32 + j] = run;
        run += cnt[t * 32 + j];
    }
    if (t == 255) offs[K] = run;
}

// ---- scatter: build code-grouped row list (atomic-free via stored rank) ----
__global__ __launch_bounds__(256) void k_scatter(const u16* __restrict__ idx16,
                                                 const u16* __restrict__ rank16,
                                                 const u32* __restrict__ offs,
                                                 u16* __restrict__ rowlist) {
    int n = blockIdx.x * 256 + threadIdx.x;
    int ix = idx16[n];
    rowlist[offs[ix] + rank16[n]] = (u16)n;
}

// ---- dw: segmented sum over code-grouped rows; run-accumulated in regs ----
__global__ __launch_bounds__(256) void k_dw(const float* __restrict__ zf,
                                            const u16* __restrict__ rowlist,
                                            const u16* __restrict__ idx16,
                                            float* __restrict__ dw) {
    const int tid = threadIdx.x;
    const int ln = tid & 63;
    const int w = (blockIdx.x * 256 + tid) >> 6;    // 0..1023
    float a0 = 0.f, a1 = 0.f;
    int prev = -1;
    for (int i = w * 16; i < w * 16 + 16; ++i) {
        int n = rowlist[i];
        int k = idx16[n];
        float v0 = zf[(size_t)n * D + ln];
        float v1 = zf[(size_t)n * D + ln + 64];
        if (k != prev) {
            if (prev >= 0) {
                atomicAdd(&dw[(size_t)prev * D + ln], a0);
                atomicAdd(&dw[(size_t)prev * D + ln + 64], a1);
            }
            prev = k; a0 = v0; a1 = v1;
        } else {
            a0 += v0; a1 += v1;
        }
    }
    if (prev >= 0) {
        atomicAdd(&dw[(size_t)prev * D + ln], a0);
        atomicAdd(&dw[(size_t)prev * D + ln + 64], a1);
    }
}

// ---- last: fused z_q_st write (overwrites z_flat region) + EMA update ----
__global__ __launch_bounds__(256) void k_last(const float* __restrict__ z_e,
                                              const float* __restrict__ cb,
                                              const u16* __restrict__ idx16,
                                              const u32* __restrict__ cnt,
                                              const float* __restrict__ ema_count,
                                              const float* __restrict__ ema_weight,
                                              float* __restrict__ out0,
                                              float* __restrict__ out2,
                                              float* __restrict__ out3,
                                              float* __restrict__ out4) {
    const int tid = threadIdx.x;
    if (blockIdx.x < 256) {
        __shared__ int idxS[64];
        const int n0 = blockIdx.x * 64;
        const int bb = n0 >> 10, p0 = n0 & 1023;
        if (tid < 64) idxS[tid] = idx16[n0 + tid];
        __syncthreads();
        const float* zb = z_e + (size_t)bb * (D * HW) + p0;
        float* ob = out0 + (size_t)bb * (D * HW) + p0;
        for (int i = tid; i < 64 * D; i += 256) {
            int d = i >> 6, r = i & 63;
            float z = zb[(size_t)d * HW + r];
            float c = cb[(size_t)idxS[r] * D + d];
            ob[(size_t)d * HW + r] = z + (c - z);
        }
    } else {
        int gid = (blockIdx.x - 256) * 256 + tid;   // over K*D
        int k = gid >> 7, d = gid & 127;
        float nc = 0.99f * ema_count[k] + 0.01f * (float)cnt[k];
        float nw = 0.99f * ema_weight[gid] + 0.01f * out4[gid];
        out4[gid] = nw;
        out2[gid] = nw / fmaxf(nc, 1.0f);
        if (d == 0) out3[k] = nc;
    }
}

extern "C" void kernel_launch(void* const* d_in, const int* in_sizes, int n_in,
                              void* d_out, int out_size, void* d_ws, size_t ws_size,
                              hipStream_t stream) {
    const float* z_e        = (const float*)d_in[0];
    const float* cb         = (const float*)d_in[1];
    const float* ema_count  = (const float*)d_in[2];
    const float* ema_weight = (const float*)d_in[3];
    float* out = (float*)d_out;
    char* ws = (char*)d_ws;

    float* cnorm   = (float*)(ws + WS_CNORM);
    u64*   packed  = (u64*)(ws + WS_PACKED);
    u32*   cnt     = (u32*)(ws + WS_CNT);
    u16*   rank16  = (u16*)(ws + WS_RANK16);
    u32*   offs    = (u32*)(ws + WS_OFFS);
    u16*   idx16   = (u16*)(ws + WS_IDX16);
    u16*   rowlist = (u16*)(ws + WS_ROWLIST);

    // fp16-split A lives in out0 (8 MB) until phase1 overwrites it with z_flat
    // (argmin is A's only consumer); B lives in out2 (4 MB) until k_last.
    u16* Ahg = (u16*)(out + OUT0);
    u16* Alg = Ahg + (size_t)NROWS * D;
    u16* Bg  = (u16*)(out + OUT2);
    float* zf = out + OUT0;

    k_prep       <<<1536,        256, 0, stream>>>(cb, z_e, Bg, cnorm, Ahg, Alg,
                                                   packed, cnt, out + OUT4);
    k_argmin_mfma<<<512,         512, 0, stream>>>(Ahg, Alg, Bg, cnorm, packed);
    k_phase1     <<<NROWS / 64,  256, 0, stream>>>(z_e, packed, out + OUT1, cnt,
                                                   idx16, rank16, zf);
    k_scan       <<<1,           256, 0, stream>>>(cnt, offs);
    k_scatter    <<<NROWS / 256, 256, 0, stream>>>(idx16, rank16, offs, rowlist);
    k_dw         <<<256,         256, 0, stream>>>(zf, rowlist, idx16, out + OUT4);
    k_last       <<<256 + (K * D) / 256, 256, 0, stream>>>(z_e, cb, idx16, cnt,
                                                   ema_count, ema_weight,
                                                   out + OUT0, out + OUT2,
                                                   out + OUT3, out + OUT4);
}